// Round 15
// baseline (499.209 us; speedup 1.0000x reference)
//
#include <hip/hip_runtime.h>
#include <hip/hip_bf16.h>

#define N_NODES 100000
#define N_PAD   100032          // 1563 * 64
#define N_EDGES 1600000
#define DIM 128
#define N_GRAPHS 128
#define NBKT 98                 // ceil(100000/1024)
#define BSTRIDE 18432           // bucket capacity (mean 16384, +16 sigma)
#define TILES (N_PAD / 16)      // 6252 row-tiles of 16
#define GRID_FUSED 1563         // one 64-row group per block
#define B1_BATCH 4096
#define B1_GRID ((N_EDGES + B1_BATCH - 1) / B1_BATCH)   // 391
#define XPREP_BLKS 12500        // N_NODES*32 / 256
#define WPREP_BLKS_1K 96        // 6*16384 / 1024
#define SUMS_BLKS_1K 16         // 16384 / 1024

typedef unsigned short u16;
typedef unsigned int u32;
typedef __attribute__((ext_vector_type(8))) short bf16x8;
typedef __attribute__((ext_vector_type(8))) unsigned short u16x8;
typedef __attribute__((ext_vector_type(4))) float f32x4;

#define MFMA(A, B, C) __builtin_amdgcn_mfma_f32_16x16x32_bf16(A, B, C, 0, 0, 0)

__device__ __forceinline__ u16 f2bf(float x) {
    u32 u = __float_as_uint(x);
    u = (u + 0x7FFFu + ((u >> 16) & 1u)) >> 16;
    return (u16)u;
}
__device__ __forceinline__ float bf2f(u16 u) {
    return __uint_as_float(((u32)u) << 16);
}

struct WPrepArgs {
    const float* w[6];
    u16* buf[6];
};

// ===========================================================================
// build_prep_a (R26): bucket1 (blocks 0..390) co-scheduled with xprep
// (blocks 391..12890). Data-independent; xprep's BW burst hides bucket1's
// atomic scatter. Bodies byte-identical to the proven kernels.
// ===========================================================================
__global__ __launch_bounds__(256) void build_prep_a(const int* __restrict__ src,
                                                    const int* __restrict__ dst,
                                                    u32* __restrict__ cursorB,
                                                    u32* __restrict__ pairs,
                                                    const float* __restrict__ x,
                                                    u16* __restrict__ hb) {
    __shared__ int lh[NBKT];
    __shared__ u32 lbase[NBKT];
    int t = threadIdx.x;
    if (blockIdx.x < B1_GRID) {
        // ---- bucket1: append packed (dstLocal<<22 | src) to coarse buckets
        if (t < NBKT) lh[t] = 0;
        __syncthreads();
        int e0 = blockIdx.x * B1_BATCH;
        int d[16], s[16], rk[16];
#pragma unroll
        for (int k = 0; k < 16; ++k) {
            int e = e0 + t + k * 256;
            if (e < N_EDGES) {
                d[k] = dst[e];
                s[k] = src[e];
                rk[k] = atomicAdd(&lh[d[k] >> 10], 1);
            }
        }
        __syncthreads();
        if (t < NBKT) lbase[t] = atomicAdd(&cursorB[t], (u32)lh[t]) + (u32)(t * BSTRIDE);
        __syncthreads();
#pragma unroll
        for (int k = 0; k < 16; ++k) {
            int e = e0 + t + k * 256;
            if (e < N_EDGES) {
                u32 pos = lbase[d[k] >> 10] + (u32)rk[k];
                pairs[pos] = ((u32)(d[k] & 1023) << 22) | (u32)s[k];
            }
        }
    } else {
        // ---- xprep: x -> bf16 hi plane (row-major)
        int i = (blockIdx.x - B1_GRID) * 256 + t;
        if (i < N_NODES * 32) {
            float4 v = ((const float4*)x)[i];
            ushort4 o;
            o.x = f2bf(v.x); o.y = f2bf(v.y); o.z = f2bf(v.z); o.w = f2bf(v.w);
            ((ushort4*)hb)[i] = o;
        }
    }
}

// ===========================================================================
// build_prep_b (R26): bucket2 (blocks 0..97) co-scheduled with wprep
// (96 blocks) and sums-zero (16 blocks). Prep backfills the idle CUs of the
// latency-bound bucket2. Bodies byte-identical to the proven kernels.
// ===========================================================================
__global__ __launch_bounds__(1024) void build_prep_b(const u32* __restrict__ cursorB,
                                                     const u32* __restrict__ pairs,
                                                     int* __restrict__ row_ptr,
                                                     int* __restrict__ csr,
                                                     WPrepArgs p,
                                                     float* __restrict__ sums) {
    __shared__ int lh[1024];
    __shared__ int rc[1024];
    __shared__ int bs[128];
    int t = threadIdx.x;
    if (blockIdx.x < NBKT) {
        // ---- bucket2: per-bucket hist + scan -> row_ptr, scatter into csr
        int b = blockIdx.x;
        if (t < 128) bs[t] = (t < NBKT) ? (int)cursorB[t] : 0;
        __syncthreads();
        for (int off = 1; off < 128; off <<= 1) {
            int v = (t < 128 && t >= off) ? bs[t - off] : 0;
            __syncthreads();
            if (t < 128) bs[t] += v;
            __syncthreads();
        }
        int cnt = (int)cursorB[b];
        int bbase = (b == 0) ? 0 : bs[b - 1];

        lh[t] = 0;
        __syncthreads();
        const u32* pb = pairs + (size_t)b * BSTRIDE;
        for (int i = t; i < cnt; i += 1024) atomicAdd(&lh[__builtin_nontemporal_load(pb + i) >> 22], 1);
        __syncthreads();

        int own = lh[t];
        for (int off = 1; off < 1024; off <<= 1) {
            int v = (t >= off) ? lh[t - off] : 0;
            __syncthreads();
            lh[t] += v;
            __syncthreads();
        }
        int excl = lh[t] - own;
        int node = b * 1024 + t;
        if (node < N_NODES) row_ptr[node] = bbase + excl;
        if (b == 0 && t == 0) row_ptr[N_NODES] = N_EDGES;
        rc[t] = bbase + excl;
        __syncthreads();

        for (int i = t; i < cnt; i += 1024) {
            u32 pr = __builtin_nontemporal_load(pb + i);
            int pos = atomicAdd(&rc[pr >> 22], 1);
            csr[pos] = (int)(pr & 0x3FFFFFu);
        }
    } else if (blockIdx.x < NBKT + WPREP_BLKS_1K) {
        // ---- wprep: fp32 W[k][n] -> hi at [n*128+k], lo at +16384
        int i = (blockIdx.x - NBKT) * 1024 + t;     // 0..98303
        int m = i >> 14;                            // matrix 0..5
        int idx = i & 16383;                        // n*128 + k
        int n = idx >> 7, k = idx & 127;
        float v = p.w[m][k * 128 + n];
        u16 hi = f2bf(v);
        p.buf[m][idx] = hi;
        p.buf[m][idx + 16384] = f2bf(v - bf2f(hi));
    } else {
        // ---- sums zero
        int i = (blockIdx.x - NBKT - WPREP_BLKS_1K) * 1024 + t;
        if (i < N_GRAPHS * DIM) sums[i] = 0.f;
    }
}

// ===========================================================================
// FUSED gin layer -- the R18/R25 winner, plus R27 pool fusion on mode 0.
// R15's pool-fusion failure is explained: it was grafted onto an already-
// spilling kernel (VGPR 128, live ~210, 30MB phantom WRITE). The current
// body runs at VGPR 60 with ~190 regs of headroom at 2 blocks/CU, so the
// identical epilogue logic (uniform-tile check + cross-row shfl reduce +
// one atomic per (graph,col); per-lane fallback on boundary tiles) fits in
// registers. mode 0 also skips the 25.6MB hout store and pools fp32 acc2
// directly (more accurate than the old bf16 round-trip). psum deleted.
// ===========================================================================
#define HS 136
__global__ __launch_bounds__(256, 2) void gin_layer(const u16* __restrict__ hin,
                                                    const int* __restrict__ rp,
                                                    const int* __restrict__ csr,
                                                    const u16* __restrict__ W1,
                                                    const float* __restrict__ b1,
                                                    const u16* __restrict__ W2,
                                                    const float* __restrict__ b2,
                                                    u16* __restrict__ hout,
                                                    const int* __restrict__ batch,
                                                    float* __restrict__ sums, int relu) {
    __shared__ u16 Hh[64 * HS];
    __shared__ u16 Hl[64 * HS];
    int tid = threadIdx.x;
    int lane = tid & 63, wave = tid >> 6;
    int m16 = lane & 15, quad = lane >> 4;
    int colBase = wave * 32;
    int t0 = blockIdx.x * 4;            // first 16-row tile
    int r0 = t0 * 16;                   // first node row of this block

    // ================= gather phase: 64 rows -> Hh (bf16) =================
    {
        int qw = tid >> 4;              // quarter-wave 0..15, one node at a time
        int f  = tid & 15;              // feature lane: cols f*8 .. f*8+7
        int nb = r0 + qw * 4;
        const u16x8* h8 = (const u16x8*)hin;
#pragma unroll
        for (int j = 0; j < 4; ++j) {
            int n = nb + j;
            int nl = qw * 4 + j;
            float a[8];
            if (n < N_NODES) {
                u16x8 sv = h8[(size_t)n * 16 + f];
#pragma unroll
                for (int r = 0; r < 8; ++r) a[r] = bf2f(sv[r]);
                int s = rp[n], e = rp[n + 1];
                int i = s;
                for (; i + 8 <= e; i += 8) {
                    u16x8 v0 = h8[(size_t)csr[i + 0] * 16 + f];
                    u16x8 v1 = h8[(size_t)csr[i + 1] * 16 + f];
                    u16x8 v2 = h8[(size_t)csr[i + 2] * 16 + f];
                    u16x8 v3 = h8[(size_t)csr[i + 3] * 16 + f];
                    u16x8 v4 = h8[(size_t)csr[i + 4] * 16 + f];
                    u16x8 v5 = h8[(size_t)csr[i + 5] * 16 + f];
                    u16x8 v6 = h8[(size_t)csr[i + 6] * 16 + f];
                    u16x8 v7 = h8[(size_t)csr[i + 7] * 16 + f];
#pragma unroll
                    for (int r = 0; r < 8; ++r)
                        a[r] += ((bf2f(v0[r]) + bf2f(v1[r])) + (bf2f(v2[r]) + bf2f(v3[r]))) +
                                ((bf2f(v4[r]) + bf2f(v5[r])) + (bf2f(v6[r]) + bf2f(v7[r])));
                }
                for (; i < e; ++i) {
                    u16x8 v = h8[(size_t)csr[i] * 16 + f];
#pragma unroll
                    for (int r = 0; r < 8; ++r) a[r] += bf2f(v[r]);
                }
            } else {
#pragma unroll
                for (int r = 0; r < 8; ++r) a[r] = 0.f;
            }
            u16x8 o;
#pragma unroll
            for (int r = 0; r < 8; ++r) o[r] = f2bf(a[r]);
            *(u16x8*)&Hh[nl * HS + f * 8] = o;
        }
    }
    __syncthreads();   // all 64 aggregated rows visible

    // ---- load A frags from LDS ----
    bf16x8 aH[4][4];
#pragma unroll
    for (int p = 0; p < 4; ++p)
#pragma unroll
        for (int kb = 0; kb < 4; ++kb)
            aH[p][kb] = *(const bf16x8*)&Hh[(p * 16 + m16) * HS + kb * 32 + quad * 8];
    __syncthreads();   // frag reads complete before epilogue1 overwrites Hh

    float b1v[2][4], b2v[2][4];
#pragma unroll
    for (int nt = 0; nt < 2; ++nt)
#pragma unroll
        for (int rg = 0; rg < 4; ++rg) {
            int col = colBase + nt * 16 + quad * 4 + rg;
            b1v[nt][rg] = b1[col];
            b2v[nt][rg] = b2[col];
        }

    f32x4 z = {0.f, 0.f, 0.f, 0.f};

    // ---- load W1 frags (pass-1 lifetime only) ----
    bf16x8 W1H[2][4], W1L[2][4];
#pragma unroll
    for (int nt = 0; nt < 2; ++nt) {
        int n = colBase + nt * 16 + m16;
#pragma unroll
        for (int kb = 0; kb < 4; ++kb) {
            int off = n * 128 + kb * 32 + quad * 8;
            W1H[nt][kb] = *(const bf16x8*)(W1 + off);
            W1L[nt][kb] = *(const bf16x8*)(W1 + off + 16384);
        }
    }

    f32x4 acc[4][2];
#pragma unroll
    for (int p = 0; p < 4; ++p) { acc[p][0] = z; acc[p][1] = z; }

    // ---- pass 1: (W1H + W1L) x aH ----
#pragma unroll
    for (int kb = 0; kb < 4; ++kb) {
#pragma unroll
        for (int p = 0; p < 4; ++p) {
            acc[p][0] = MFMA(W1H[0][kb], aH[p][kb], acc[p][0]);
            acc[p][1] = MFMA(W1H[1][kb], aH[p][kb], acc[p][1]);
            acc[p][0] = MFMA(W1L[0][kb], aH[p][kb], acc[p][0]);
            acc[p][1] = MFMA(W1L[1][kb], aH[p][kb], acc[p][1]);
        }
    }

    // ---- epilogue 1: bias+relu+split -> LDS ----
#pragma unroll
    for (int p = 0; p < 4; ++p) {
#pragma unroll
        for (int nt = 0; nt < 2; ++nt) {
            ushort4 hv, lv;
#pragma unroll
            for (int rg = 0; rg < 4; ++rg) {
                float v = fmaxf(acc[p][nt][rg] + b1v[nt][rg], 0.f);
                u16 hi = f2bf(v);
                ((u16*)&hv)[rg] = hi;
                ((u16*)&lv)[rg] = f2bf(v - bf2f(hi));
            }
            int off = (p * 16 + m16) * HS + colBase + nt * 16 + quad * 4;
            *(ushort4*)&Hh[off] = hv;
            *(ushort4*)&Hl[off] = lv;
        }
    }
    __syncthreads();   // H visible to all waves

    // ---- load W2 frags (pass-2 lifetime only) ----
    bf16x8 W2H[2][4], W2L[2][4];
#pragma unroll
    for (int nt = 0; nt < 2; ++nt) {
        int n = colBase + nt * 16 + m16;
#pragma unroll
        for (int kb = 0; kb < 4; ++kb) {
            int off = n * 128 + kb * 32 + quad * 8;
            W2H[nt][kb] = *(const bf16x8*)(W2 + off);
            W2L[nt][kb] = *(const bf16x8*)(W2 + off + 16384);
        }
    }

    // ---- pass 2: W2 x H (H hi/lo) ----
    f32x4 acc2[4][2];
#pragma unroll
    for (int p = 0; p < 4; ++p) { acc2[p][0] = z; acc2[p][1] = z; }
#pragma unroll
    for (int kb = 0; kb < 4; ++kb) {
#pragma unroll
        for (int p = 0; p < 4; ++p) {
            int off = (p * 16 + m16) * HS + kb * 32 + quad * 8;
            bf16x8 hH = *(const bf16x8*)(&Hh[off]);
            bf16x8 hL = *(const bf16x8*)(&Hl[off]);
            acc2[p][0] = MFMA(W2H[0][kb], hH, acc2[p][0]);
            acc2[p][1] = MFMA(W2H[1][kb], hH, acc2[p][1]);
            acc2[p][0] = MFMA(W2H[0][kb], hL, acc2[p][0]);
            acc2[p][1] = MFMA(W2H[1][kb], hL, acc2[p][1]);
            acc2[p][0] = MFMA(W2L[0][kb], hH, acc2[p][0]);
            acc2[p][1] = MFMA(W2L[1][kb], hH, acc2[p][1]);
        }
    }

    // ---- epilogue 2 ----
    if (relu) {
        // layers 0,1: bias + relu -> bf16 global (feeds next layer's gather)
#pragma unroll
        for (int p = 0; p < 4; ++p) {
            size_t row = (size_t)(t0 + p) * 16 + m16;
#pragma unroll
            for (int nt = 0; nt < 2; ++nt) {
                int col = colBase + nt * 16 + quad * 4;
                ushort4 o;
#pragma unroll
                for (int rg = 0; rg < 4; ++rg)
                    ((u16*)&o)[rg] = f2bf(fmaxf(acc2[p][nt][rg] + b2v[nt][rg], 0.f));
                *(ushort4*)(hout + row * 128 + col) = o;
            }
        }
    } else {
        // layer 2: fused mean-pool stage 1 -- never materialize node_emb.
#pragma unroll
        for (int p = 0; p < 4; ++p) {
            int row = (t0 + p) * 16 + m16;
            int g = (row < N_NODES) ? batch[row] : -1;
            int gmin = g, gmax = g;
#pragma unroll
            for (int d = 1; d < 16; d <<= 1) {
                gmin = min(gmin, __shfl_xor(gmin, d));
                gmax = max(gmax, __shfl_xor(gmax, d));
            }
            if (gmin == gmax && gmin >= 0) {
                // uniform tile: cross-row reduce, 1 atomic per col
#pragma unroll
                for (int nt = 0; nt < 2; ++nt)
#pragma unroll
                    for (int rg = 0; rg < 4; ++rg) {
                        float sv = acc2[p][nt][rg] + b2v[nt][rg];
#pragma unroll
                        for (int d = 1; d < 16; d <<= 1) sv += __shfl_xor(sv, d);
                        if (m16 == nt * 4 + rg)
                            atomicAdd(&sums[gmin * 128 + colBase + nt * 16 + quad * 4 + rg], sv);
                    }
            } else if (g >= 0) {
                // boundary / tail tile: per-lane atomics (~2% of tiles)
#pragma unroll
                for (int nt = 0; nt < 2; ++nt)
#pragma unroll
                    for (int rg = 0; rg < 4; ++rg)
                        atomicAdd(&sums[g * 128 + colBase + nt * 16 + quad * 4 + rg],
                                  acc2[p][nt][rg] + b2v[nt][rg]);
            }
        }
    }
}

// pool stage 2: counts by binary search, divide.
__global__ __launch_bounds__(128) void pdiv_kernel(const float* __restrict__ sums,
                                                   const int* __restrict__ batch,
                                                   float* __restrict__ out) {
    __shared__ int sB[2];
    int g = blockIdx.x;
    if (threadIdx.x < 2) {
        int target = g + threadIdx.x;
        int lo = 0, hi = N_NODES;
        while (lo < hi) {
            int m = (lo + hi) >> 1;
            if (batch[m] < target) lo = m + 1; else hi = m;
        }
        sB[threadIdx.x] = lo;
    }
    __syncthreads();
    float cnt = (float)(sB[1] - sB[0]);
    out[g * 128 + threadIdx.x] = sums[g * 128 + threadIdx.x] / fmaxf(cnt, 1.f);
}

// ===========================================================================
extern "C" void kernel_launch(void* const* d_in, const int* in_sizes, int n_in,
                              void* d_out, int out_size, void* d_ws, size_t ws_size,
                              hipStream_t stream) {
    const float* x     = (const float*)d_in[0];
    const int*   ei    = (const int*)d_in[1];
    const int*   batch = (const int*)d_in[2];
    const int*   eSrc  = ei;
    const int*   eDst  = ei + N_EDGES;

    const float* W1[3] = {(const float*)d_in[3], (const float*)d_in[7],  (const float*)d_in[11]};
    const float* b1[3] = {(const float*)d_in[4], (const float*)d_in[8],  (const float*)d_in[12]};
    const float* W2[3] = {(const float*)d_in[5], (const float*)d_in[9],  (const float*)d_in[13]};
    const float* b2[3] = {(const float*)d_in[6], (const float*)d_in[10], (const float*)d_in[14]};

    // workspace layout. Ping-pong h-planes: plane B aliases the old P2 fp32
    // region (pairs also aliases it -- temporally disjoint: CSR build
    // completes before layer 0 runs).
    float* P2 = (float*)d_ws;                          // [N_PAD,128] fp32 region
    u16*   planeB = (u16*)P2;                          // layer ping-pong plane B
    u16*   planeA = (u16*)(P2 + (size_t)N_PAD * DIM);  // plane A (xprep target)
    u16*   Ah = planeA + (size_t)N_PAD * DIM;          // (unused, layout keep)
    u16*   Wb = Ah + (size_t)N_PAD * DIM;              // 6 x 32768 u16
    int*   row_ptr = (int*)(Wb + 6 * 32768);           // N_NODES + 8
    u32*   cursorB = (u32*)(row_ptr + N_NODES + 8);    // 128
    int*   csr     = (int*)(cursorB + 128);            // N_EDGES
    float* sums    = (float*)(csr + N_EDGES);          // [128,128]
    u32*   pairs   = (u32*)P2;                         // aliases plane B (disjoint lifetime)

    WPrepArgs wp;
    for (int l = 0; l < 3; ++l) {
        wp.w[2 * l]       = W1[l];
        wp.w[2 * l + 1]   = W2[l];
        wp.buf[2 * l]     = Wb + (size_t)(2 * l) * 32768;
        wp.buf[2 * l + 1] = Wb + (size_t)(2 * l + 1) * 32768;
    }

    // ---- stage A: bucket1 || xprep (independent) ----
    hipMemsetAsync(cursorB, 0, 128 * sizeof(u32), stream);
    build_prep_a<<<B1_GRID + XPREP_BLKS, 256, 0, stream>>>(eSrc, eDst, cursorB, pairs, x, planeA);

    // ---- stage B: bucket2 || wprep || sums-zero ----
    build_prep_b<<<NBKT + WPREP_BLKS_1K + SUMS_BLKS_1K, 1024, 0, stream>>>(cursorB, pairs, row_ptr, csr, wp, sums);

    // ---- 3 fused layers, ping-pong planes; layer 2 pools directly ----
    u16* hin  = planeA;
    u16* hout = planeB;
    for (int l = 0; l < 3; ++l) {
        gin_layer<<<GRID_FUSED, 256, 0, stream>>>(hin, row_ptr, csr,
                                                  Wb + (size_t)(2 * l) * 32768, b1[l],
                                                  Wb + (size_t)(2 * l + 1) * 32768, b2[l],
                                                  hout, batch, sums, (l < 2) ? 1 : 0);
        u16* tmp = hin; hin = hout; hout = tmp;
    }
    pdiv_kernel<<<N_GRAPHS, 128, 0, stream>>>(sums, batch, (float*)d_out);
}